// Round 7
// baseline (3141.841 us; speedup 1.0000x reference)
//
#include <hip/hip_runtime.h>
#include <stdint.h>

#define N_TOK 4096
#define DIM   256
#define NH    4
#define DH    64
#define TOPK  30
#define CANDN 40      // candidate margin: approx-top-40 superset of exact top-30
#define CANDCAP 256   // per-row candidate buffer capacity
#define ATT_SCALE 0.25f
#define LN_EPS 1e-5f

typedef __attribute__((ext_vector_type(8))) short bf16x8;  // 8 bf16 in 4 VGPRs
typedef __attribute__((ext_vector_type(4))) float f32x4;

static __device__ __forceinline__ ushort f2bf(float f) {   // RNE
    uint x = __float_as_uint(f);
    return (ushort)((x + 0x7FFFu + ((x >> 16) & 1u)) >> 16);
}
static __device__ __forceinline__ bf16x8 load_frag(const ushort* p) {
    union { int4 i; bf16x8 f; } u;
    u.i = *reinterpret_cast<const int4*>(p);
    return u.f;
}
static __device__ __forceinline__ uint s16key(uint u) {    // bf16 bits -> sortable u16
    return (u & 0x8000u) ? (u ^ 0xFFFFu) : (u | 0x8000u);
}

// ---------------------------------------------------------------------------
// Fused q+k fp32 GEMM NT (exactness needed for rescoring).
// ---------------------------------------------------------------------------
#define BK 32
__global__ __launch_bounds__(256) void qk_gemm_f32(
    const float* __restrict__ query_in, const float* __restrict__ key_in,
    const float* __restrict__ Wq, const float* __restrict__ bq,
    const float* __restrict__ Wk, const float* __restrict__ bk,
    float* __restrict__ qf, float* __restrict__ kf,
    ushort* __restrict__ qb, ushort* __restrict__ kb)
{
    const int j0g = blockIdx.x * 64;          // 0..511
    const int sel = j0g >> 8;                 // 0=q, 1=k
    const int j0  = j0g & 255;
    const float* A    = sel ? key_in : query_in;
    const float* W    = sel ? Wk : Wq;
    const float* bias = sel ? bk : bq;
    float*  outF = sel ? kf : qf;
    ushort* outB = sel ? kb : qb;

    __shared__ float As[BK][64 + 4];
    __shared__ float Ws[BK][64 + 4];
    const int tid = threadIdx.x;
    const int tx = tid & 15;
    const int ty = tid >> 4;
    const int i0 = blockIdx.y * 64;

    float acc[4][4];
#pragma unroll
    for (int r = 0; r < 4; r++)
#pragma unroll
        for (int c = 0; c < 4; c++) acc[r][c] = 0.f;

    for (int k0 = 0; k0 < DIM; k0 += BK) {
#pragma unroll
        for (int u = 0; u < 2; u++) {
            const int f = u * 256 + tid;
            const int r = f >> 3;
            const int c = (f & 7) * 4;
            float4 va = *reinterpret_cast<const float4*>(A + (size_t)(i0 + r) * DIM + k0 + c);
            As[c + 0][r] = va.x; As[c + 1][r] = va.y;
            As[c + 2][r] = va.z; As[c + 3][r] = va.w;
            float4 vw = *reinterpret_cast<const float4*>(W + (size_t)(j0 + r) * DIM + k0 + c);
            Ws[c + 0][r] = vw.x; Ws[c + 1][r] = vw.y;
            Ws[c + 2][r] = vw.z; Ws[c + 3][r] = vw.w;
        }
        __syncthreads();
#pragma unroll
        for (int kk = 0; kk < BK; kk++) {
            const float4 a4 = *reinterpret_cast<const float4*>(&As[kk][ty * 4]);
            const float4 b4 = *reinterpret_cast<const float4*>(&Ws[kk][tx * 4]);
            const float ar[4] = {a4.x, a4.y, a4.z, a4.w};
            const float br[4] = {b4.x, b4.y, b4.z, b4.w};
#pragma unroll
            for (int r = 0; r < 4; r++)
#pragma unroll
                for (int c = 0; c < 4; c++) acc[r][c] += ar[r] * br[c];
        }
        __syncthreads();
    }

#pragma unroll
    for (int r = 0; r < 4; r++) {
        const int gi = i0 + ty * 4 + r;
#pragma unroll
        for (int c = 0; c < 4; c++) {
            const int gj = j0 + tx * 4 + c;
            float v = acc[r][c] + bias[gj];
            outF[(size_t)gi * DIM + gj] = v;
            outB[(size_t)gi * DIM + gj] = f2bf(v);
        }
    }
}

// ---------------------------------------------------------------------------
// Cast fp32->bf16 (value_in, Wv, Wo) + zero-init rowmax/cnt (128 KB).
// ---------------------------------------------------------------------------
#define NCAST 294912          // 262144 + 16384 + 16384 float4 tasks
#define NINIT 8192            // 32768 u32 / 4
__global__ __launch_bounds__(256) void cast_init_kernel(
    const float* __restrict__ value_in, const float* __restrict__ Wv,
    const float* __restrict__ Wo, ushort* __restrict__ value_b,
    ushort* __restrict__ Wv_b, ushort* __restrict__ Wo_b,
    uint4* __restrict__ initz)
{
    const int id4 = blockIdx.x * 256 + threadIdx.x;
    if (id4 >= NCAST) {
        initz[id4 - NCAST] = (uint4){0u, 0u, 0u, 0u};
        return;
    }
    const int NV = 262144, NW = 16384;
    const float* src; ushort* dst; int off;
    if (id4 < NV)            { src = value_in; dst = value_b; off = id4; }
    else if (id4 < NV + NW)  { src = Wv; dst = Wv_b; off = id4 - NV; }
    else                     { src = Wo; dst = Wo_b; off = id4 - NV - NW; }
    float4 v = reinterpret_cast<const float4*>(src)[off];
    ushort4 o = {f2bf(v.x), f2bf(v.y), f2bf(v.z), f2bf(v.w)};
    reinterpret_cast<ushort4*>(dst)[off] = o;
}

// ---------------------------------------------------------------------------
// bf16 MFMA GEMM NT (v-projection and out-projection).
// ---------------------------------------------------------------------------
__global__ __launch_bounds__(256) void mfma_gemm(
    const ushort* __restrict__ A, const ushort* __restrict__ B,
    const float* __restrict__ bias, const float* __restrict__ addX,
    float* __restrict__ outF)
{
    const int lane = threadIdx.x & 63;
    const int wv   = threadIdx.x >> 6;
    const int i0   = blockIdx.y * 64 + wv * 16;
    const int j0   = blockIdx.x * 64;
    const int r = lane & 15, q = lane >> 4;

    f32x4 acc[4];
#pragma unroll
    for (int b = 0; b < 4; b++) acc[b] = (f32x4){0.f, 0.f, 0.f, 0.f};

#pragma unroll
    for (int ks = 0; ks < 8; ks++) {
        const int kk = ks * 32 + q * 8;
        bf16x8 af = load_frag(A + (size_t)(i0 + r) * DIM + kk);
        bf16x8 bfr[4];
#pragma unroll
        for (int jt = 0; jt < 4; jt++)
            bfr[jt] = load_frag(B + (size_t)(j0 + jt * 16 + r) * DIM + kk);
#pragma unroll
        for (int jt = 0; jt < 4; jt++)
            acc[jt] = __builtin_amdgcn_mfma_f32_16x16x32_bf16(af, bfr[jt], acc[jt], 0, 0, 0);
    }

#pragma unroll
    for (int jt = 0; jt < 4; jt++) {
        const int gj = j0 + jt * 16 + r;          // col = lane&15
        const float bv = bias[gj];
#pragma unroll
        for (int rg = 0; rg < 4; rg++) {          // row = (lane>>4)*4+reg
            const int gi = i0 + q * 4 + rg;
            float v = acc[jt][rg] + bv;
            if (addX) v += addX[(size_t)gi * DIM + gj];
            outF[(size_t)gi * DIM + gj] = v;
        }
    }
}

// ---------------------------------------------------------------------------
// Shared MFMA score-tile body: 32 rows x 128 cols per wave (one head slice).
// ---------------------------------------------------------------------------
static __device__ __forceinline__ void score_tile(
    const ushort* qb, const ushort* kb, int i0, int j0, int koff,
    int r, int q, f32x4 acc[2][8])
{
#pragma unroll
    for (int a = 0; a < 2; a++)
#pragma unroll
        for (int b = 0; b < 8; b++) acc[a][b] = (f32x4){0.f, 0.f, 0.f, 0.f};
#pragma unroll
    for (int ks = 0; ks < 2; ks++) {
        const int kk = koff + ks * 32 + q * 8;
        bf16x8 af[2], bfr[8];
#pragma unroll
        for (int mt = 0; mt < 2; mt++)
            af[mt] = load_frag(qb + (size_t)(i0 + mt * 16 + r) * DIM + kk);
#pragma unroll
        for (int jt = 0; jt < 8; jt++)
            bfr[jt] = load_frag(kb + (size_t)(j0 + jt * 16 + r) * DIM + kk);
#pragma unroll
        for (int mt = 0; mt < 2; mt++)
#pragma unroll
            for (int jt = 0; jt < 8; jt++)
                acc[mt][jt] = __builtin_amdgcn_mfma_f32_16x16x32_bf16(
                    af[mt], bfr[jt], acc[mt][jt], 0, 0, 0);
    }
}

// ---------------------------------------------------------------------------
// Pass 1: per-row max approx-score key via shfl-max + global atomicMax.
// Writes NOTHING else (kills the 128 MB key tensor).
// ---------------------------------------------------------------------------
__global__ __launch_bounds__(256) void scores_max(
    const ushort* __restrict__ qb, const ushort* __restrict__ kb,
    uint* __restrict__ rowmaxU)
{
    const int lane = threadIdx.x & 63;
    const int wv   = threadIdx.x >> 6;
    const int h    = blockIdx.z;
    const int i0   = blockIdx.y * 128 + wv * 32;
    const int j0   = blockIdx.x * 128;
    const int r = lane & 15, q = lane >> 4;

    f32x4 acc[2][8];
    score_tile(qb, kb, i0, j0, h * DH, r, q, acc);

#pragma unroll
    for (int mt = 0; mt < 2; mt++)
#pragma unroll
        for (int rg = 0; rg < 4; rg++) {
            float m = acc[mt][0][rg];
#pragma unroll
            for (int jt = 1; jt < 8; jt++) m = fmaxf(m, acc[mt][jt][rg]);
            // reduce across the 16 r-lanes of this q-group (lane bits 0..3)
#pragma unroll
            for (int off = 1; off < 16; off <<= 1)
                m = fmaxf(m, __shfl_xor(m, off));
            if (r == 0) {
                const int row = h * N_TOK + i0 + mt * 16 + q * 4 + rg;
                atomicMax(&rowmaxU[row], s16key(f2bf(m)));
            }
        }
}

// ---------------------------------------------------------------------------
// Pass 2: recompute identical scores; append keys within 255 ulps of the row
// max (empirically ~100/row, r3 counters) as (key<<12 | j) into a 256-entry
// per-row candidate buffer. ~6.5 MB of writes instead of 128 MB.
// ---------------------------------------------------------------------------
__global__ __launch_bounds__(256) void scores_cand(
    const ushort* __restrict__ qb, const ushort* __restrict__ kb,
    const uint* __restrict__ rowmaxU, uint* __restrict__ cntU,
    uint* __restrict__ candb)
{
    const int lane = threadIdx.x & 63;
    const int wv   = threadIdx.x >> 6;
    const int h    = blockIdx.z;
    const int i0   = blockIdx.y * 128 + wv * 32;
    const int j0   = blockIdx.x * 128;
    const int r = lane & 15, q = lane >> 4;

    f32x4 acc[2][8];
    score_tile(qb, kb, i0, j0, h * DH, r, q, acc);

#pragma unroll
    for (int mt = 0; mt < 2; mt++)
#pragma unroll
        for (int rg = 0; rg < 4; rg++) {
            const int row = h * N_TOK + i0 + mt * 16 + q * 4 + rg;
            const uint mxr = rowmaxU[row];
#pragma unroll
            for (int jt = 0; jt < 8; jt++) {
                const uint key = s16key(f2bf(acc[mt][jt][rg]));
                if (mxr - key < 255u) {
                    uint pos = atomicAdd(&cntU[row], 1u);
                    if (pos < CANDCAP)
                        candb[(size_t)row * CANDCAP + pos] =
                            (key << 12) | (uint)(j0 + jt * 16 + r);
                }
            }
        }
}

// ---------------------------------------------------------------------------
// Selection v5: reads <=256 candidates/row (not 4096 keys). Histogram/scan on
// candidates -> rank-40 threshold -> exact fp32 rescore -> bitonic sort ->
// softmax -> ctx + (fused attn row write | pval/pidx). Wave-uniform fallback
// (cnt<40 or overflow): exact fp32 recompute of the whole row (~never).
// ---------------------------------------------------------------------------
__global__ __launch_bounds__(256) void select_kernel(
    const uint* __restrict__ rowmaxU, const uint* __restrict__ cntU,
    const uint* __restrict__ candb, const float* __restrict__ qf,
    const float* __restrict__ kf, const float* __restrict__ vf,
    float* __restrict__ pval, int* __restrict__ pidx,
    ushort* __restrict__ ctxb, float* __restrict__ attnRow)
{
    const int lane = threadIdx.x & 63;
    const int wv   = threadIdx.x >> 6;
    const int row  = blockIdx.x * 4 + wv;      // 0..16383
    const int h    = row >> 12;
    const int i    = row & (N_TOK - 1);

    __shared__ uint  hist[4][256];
    __shared__ uint  cand[4][64];
    __shared__ uint  ccnt[4];
    __shared__ float pw[4][TOPK];
    __shared__ int   jw[4][TOPK];
    __shared__ __align__(16) float qsh[4][DH];

    qsh[wv][lane] = qf[(size_t)i * DIM + h * DH + lane];
    if (lane == 0) ccnt[wv] = 0;
#pragma unroll
    for (int b = 0; b < 4; b++) hist[wv][b * 64 + lane] = 0u;  // stride-64: free

    const uint cnt = cntU[row];
    const uint mxr = rowmaxU[row];

    // early coalesced zero of the final attn row (drains while we compute)
    if (attnRow) {
        float4* rowg = reinterpret_cast<float4*>(attnRow + (size_t)row * N_TOK);
        const float4 z = {0.f, 0.f, 0.f, 0.f};
#pragma unroll
        for (int tt = 0; tt < 16; tt++) rowg[tt * 64 + lane] = z;
    }

    if (cnt >= CANDN && cnt <= CANDCAP) {
        // ---------------- primary: candidates only ----------------
        uint ce[4]; int ne = 0;
        for (int e = lane; e < (int)cnt; e += 64) {
            uint w = candb[(size_t)row * CANDCAP + e];
            ce[ne++] = w;
            atomicAdd(&hist[wv][mxr - (w >> 12)], 1u);   // d <= 254 by filter
        }
        // prefix-scan bins, find rank-CANDN edge
        const uint c0 = hist[wv][lane * 4 + 0];
        const uint c1 = hist[wv][lane * 4 + 1];
        const uint c2 = hist[wv][lane * 4 + 2];
        const uint c3 = hist[wv][lane * 4 + 3];
        const uint segs = c0 + c1 + c2 + c3;
        uint scan = segs;
#pragma unroll
        for (int d = 1; d < 64; d <<= 1) {
            uint y = (uint)__shfl_up((int)scan, d);
            if (lane >= d) scan += y;
        }
        const uint excl = scan - segs;
        const bool crossing = (excl < CANDN) && (scan >= CANDN);
        unsigned long long bal = __ballot(crossing);
        int t = 254;                      // degenerate-safe default: whole window
        if (bal != 0ull) {
            const int srcLane = __ffsll(bal) - 1;
            int tloc = lane * 4;
            if (crossing) {
                uint cum = excl + c0;
                if (cum < CANDN) { tloc++; cum += c1;
                    if (cum < CANDN) { tloc++; cum += c2;
                        if (cum < CANDN) { tloc++; } } }
            }
            t = __shfl(tloc, srcLane);
        }
        const uint T = mxr - (uint)t;
        // compact candidates >= T
        for (int e = 0; e < ne; e++) {
            if ((ce[e] >> 12) >= T) {
                uint pos = atomicAdd(&ccnt[wv], 1u);
                if (pos < 64u) cand[wv][pos] = ce[e] & 0xFFFu;
            }
        }
    } else {
        // ---------------- fallback: exact fp32 full-row recompute ----------
        uint kwf[32];
        const float4* qr = reinterpret_cast<const float4*>(qsh[wv]);
        for (int tt = 0; tt < 64; tt++) {
            const int j = tt * 64 + lane;
            const float4* kr = reinterpret_cast<const float4*>(kf + (size_t)j * DIM + h * DH);
            float s = 0.f;
#pragma unroll
            for (int d = 0; d < 16; d++) {
                float4 a = qr[d], bb = kr[d];
                s += a.x * bb.x; s += a.y * bb.y; s += a.z * bb.z; s += a.w * bb.w;
            }
            const uint key = s16key(f2bf(s));
            if (tt & 1) kwf[tt >> 1] |= key << 16;
            else        kwf[tt >> 1] = key;
        }
        uint lo = 0;
#pragma unroll
        for (int b = 15; b >= 0; b--) {
            uint trial = lo | (1u << b);
            int c = 0;
#pragma unroll
            for (int w = 0; w < 32; w++) {
                c += ((kwf[w] & 0xFFFFu) >= trial) ? 1 : 0;
                c += ((kwf[w] >> 16)     >= trial) ? 1 : 0;
            }
#pragma unroll
            for (int off = 32; off; off >>= 1) c += __shfl_xor(c, off);
            if (c >= CANDN) lo = trial;
        }
        for (int tt = 0; tt < 64; tt++) {
            const uint key = (tt & 1) ? (kwf[tt >> 1] >> 16) : (kwf[tt >> 1] & 0xFFFFu);
            if (key >= lo) {
                uint pos = atomicAdd(&ccnt[wv], 1u);
                if (pos < 64u) cand[wv][pos] = (uint)(tt * 64 + lane);
            }
        }
    }

    const int m = (int)min(ccnt[wv], 64u);

    // exact fp32 rescore of candidate `lane`
    unsigned long long ukey = 0ull;
    if (lane < m) {
        const int j = (int)cand[wv][lane];
        const float4* kr = reinterpret_cast<const float4*>(kf + (size_t)j * DIM + h * DH);
        const float4* qr = reinterpret_cast<const float4*>(qsh[wv]);
        float s = 0.f;
#pragma unroll
        for (int d = 0; d < 16; d++) {
            float4 a = qr[d], bb = kr[d];
            s += a.x * bb.x; s += a.y * bb.y; s += a.z * bb.z; s += a.w * bb.w;
        }
        uint bits = __float_as_uint(s);
        uint s32 = (bits & 0x80000000u) ? ~bits : (bits | 0x80000000u);
        ukey = ((unsigned long long)s32 << 12) | (unsigned long long)(4095 - j);
    }

    // bitonic sort ascending (key: score, tie: smaller index wins)
#pragma unroll
    for (int k = 2; k <= 64; k <<= 1) {
#pragma unroll
        for (int jj = k >> 1; jj > 0; jj >>= 1) {
            unsigned long long o = __shfl_xor(ukey, jj);
            bool keepMax = ((lane & jj) != 0) ^ ((lane & k) != 0);
            ukey = keepMax ? (ukey > o ? ukey : o) : (ukey < o ? ukey : o);
        }
    }

    const int rank = 63 - lane;
    const int jsel = 4095 - (int)(ukey & 0xFFFull);
    uint s32b = (uint)(ukey >> 12);
    uint fb = (s32b & 0x80000000u) ? (s32b ^ 0x80000000u) : ~s32b;
    const float sc = __uint_as_float(fb);
    const float stop = __shfl(sc, 63);

    float e = (rank < TOPK) ? __expf((sc - stop) * ATT_SCALE) : 0.f;
    float esum = e;
#pragma unroll
    for (int off = 32; off; off >>= 1) esum += __shfl_xor(esum, off);
    const float p = e / esum;

    if (rank < TOPK) {
        pw[wv][rank] = p; jw[wv][rank] = jsel;
        if (pval) {
            pval[(size_t)row * 32 + rank] = p;
            pidx[(size_t)row * 32 + rank] = jsel;
        }
    }

    // sparse ctx
    float a = 0.f;
#pragma unroll
    for (int c = 0; c < TOPK; c++)
        a += pw[wv][c] * vf[(size_t)jw[wv][c] * DIM + h * DH + lane];
    ctxb[(size_t)i * DIM + h * DH + lane] = f2bf(a);

    if (attnRow) {
        asm volatile("s_waitcnt vmcnt(0)" ::: "memory");   // zeros drained
        if (rank < TOPK)
            attnRow[(size_t)row * N_TOK + jsel] = p;
    }
}

// ---------------------------------------------------------------------------
// attn_write (small-ws fallback path only).
// ---------------------------------------------------------------------------
__global__ __launch_bounds__(256) void attn_write(
    const float* __restrict__ pval, const int* __restrict__ pidx,
    float* __restrict__ attnF)
{
    __shared__ __align__(16) float rb[4][N_TOK];
    const int tid = threadIdx.x;
    const int r0 = blockIdx.x * 4;

    float4* rb4 = reinterpret_cast<float4*>(&rb[0][0]);
    const float4 z = {0.f, 0.f, 0.f, 0.f};
#pragma unroll
    for (int t = 0; t < 16; t++) rb4[t * 256 + tid] = z;
    __syncthreads();
    if (tid < 4 * TOPK) {
        const int w = tid / TOPK, c = tid % TOPK;
        rb[w][pidx[(size_t)(r0 + w) * 32 + c]] = pval[(size_t)(r0 + w) * 32 + c];
    }
    __syncthreads();
#pragma unroll
    for (int w = 0; w < 4; w++) {
        float4* grow = reinterpret_cast<float4*>(attnF + (size_t)(r0 + w) * N_TOK);
#pragma unroll
        for (int t = 0; t < 4; t++)
            grow[t * 256 + tid] = rb4[w * 1024 + t * 256 + tid];
    }
}

// ---------------------------------------------------------------------------
// Row LayerNorm (biased var), in-place on fp32 resid. One wave per row.
// ---------------------------------------------------------------------------
__global__ __launch_bounds__(64) void ln_kernel(
    float* __restrict__ resb, const float* __restrict__ g,
    const float* __restrict__ b)
{
    const int i = blockIdx.x, lane = threadIdx.x;
    float4* rowp = reinterpret_cast<float4*>(resb + (size_t)i * DIM);
    float4 x = rowp[lane];
    float s  = x.x + x.y + x.z + x.w;
    float sq = x.x * x.x + x.y * x.y + x.z * x.z + x.w * x.w;
#pragma unroll
    for (int off = 32; off; off >>= 1) {
        s  += __shfl_xor(s, off);
        sq += __shfl_xor(sq, off);
    }
    const float mu  = s * (1.f / DIM);
    const float var = sq * (1.f / DIM) - mu * mu;
    const float rstd = rsqrtf(var + LN_EPS);
    const int col = lane * 4;
    float4 o;
    o.x = (x.x - mu) * rstd * g[col + 0] + b[col + 0];
    o.y = (x.y - mu) * rstd * g[col + 1] + b[col + 1];
    o.z = (x.z - mu) * rstd * g[col + 2] + b[col + 2];
    o.w = (x.w - mu) * rstd * g[col + 3] + b[col + 3];
    rowp[lane] = o;
}

// ---------------------------------------------------------------------------
extern "C" void kernel_launch(void* const* d_in, const int* in_sizes, int n_in,
                              void* d_out, int out_size, void* d_ws, size_t ws_size,
                              hipStream_t stream)
{
    const float* key_in   = (const float*)d_in[0];
    const float* value_in = (const float*)d_in[1];
    const float* query_in = (const float*)d_in[2];
    const float* Wq = (const float*)d_in[3];
    const float* bq = (const float*)d_in[4];
    const float* Wk = (const float*)d_in[5];
    const float* bk = (const float*)d_in[6];
    const float* Wv = (const float*)d_in[7];
    const float* bv = (const float*)d_in[8];
    const float* Wo = (const float*)d_in[9];
    const float* bo = (const float*)d_in[10];
    const float* ln_g = (const float*)d_in[11];
    const float* ln_b = (const float*)d_in[12];

    float* outF  = (float*)d_out;                     // (N, D) fp32
    float* attnF = outF + (size_t)N_TOK * DIM;        // (H, N, N) fp32

    // scratch layout (38 MB): candb 16M | qf 4M | kf 4M | vf 4M | qb 2M |
    // kb 2M | ctxb 2M | value_b 2M | Wv_b/Wo_b 256K | rowmax 64K | cnt 64K
    const size_t NEED = 40u << 20;
    const bool usews = (ws_size >= NEED);
    char* base = usews ? (char*)d_ws : (char*)attnF;  // fallback: inside attnF

    uint*   candb   = (uint*)base;
    float*  qf      = (float*)(base + (16u << 20));
    float*  kf      = (float*)(base + (20u << 20));
    float*  vf      = (float*)(base + (24u << 20));
    ushort* qb      = (ushort*)(base + (28u << 20));
    ushort* kb      = (ushort*)(base + (30u << 20));
    ushort* ctxb    = (ushort*)(base + (32u << 20));
    ushort* value_b = (ushort*)(base + (34u << 20));
    ushort* Wv_b    = (ushort*)(base + (36u << 20));
    ushort* Wo_b    = (ushort*)(base + (36u << 20) + 131072);
    uint*   rowmaxU = (uint*)(base + (37u << 20));
    uint*   cntU    = (uint*)(base + (37u << 20) + 65536);
    float*  pval    = (float*)(base + (38u << 20));   // fallback path only
    int*    pidx    = (int*)(base + (38u << 20) + (2u << 20));

    cast_init_kernel<<<(NCAST + NINIT) / 256, 256, 0, stream>>>(
        value_in, Wv, Wo, value_b, Wv_b, Wo_b, (uint4*)rowmaxU);
    qk_gemm_f32<<<dim3(8, 64), 256, 0, stream>>>(
        query_in, key_in, Wq, bq, Wk, bk, qf, kf, qb, kb);
    mfma_gemm<<<dim3(4, 64), 256, 0, stream>>>(value_b, Wv_b, bv, nullptr, vf);

    scores_max<<<dim3(32, 32, NH), 256, 0, stream>>>(qb, kb, rowmaxU);
    scores_cand<<<dim3(32, 32, NH), 256, 0, stream>>>(qb, kb, rowmaxU, cntU, candb);

    if (usews) {
        select_kernel<<<dim3(N_TOK * NH / 4), 256, 0, stream>>>(
            rowmaxU, cntU, candb, qf, kf, vf, nullptr, nullptr, ctxb, attnF);
        mfma_gemm<<<dim3(4, 64), 256, 0, stream>>>(ctxb, Wo_b, bo, query_in, outF);
        ln_kernel<<<N_TOK, 64, 0, stream>>>(outF, ln_g, ln_b);
    } else {
        select_kernel<<<dim3(N_TOK * NH / 4), 256, 0, stream>>>(
            rowmaxU, cntU, candb, qf, kf, vf, pval, pidx, ctxb, nullptr);
        mfma_gemm<<<dim3(4, 64), 256, 0, stream>>>(ctxb, Wo_b, bo, query_in, outF);
        ln_kernel<<<N_TOK, 64, 0, stream>>>(outF, ln_g, ln_b);
        attn_write<<<N_TOK * NH / 4, 256, 0, stream>>>(pval, pidx, attnF);
    }
}

// Round 8
// 602.681 us; speedup vs baseline: 5.2131x; 5.2131x over previous
//
#include <hip/hip_runtime.h>
#include <stdint.h>

#define N_TOK 4096
#define DIM   256
#define NH    4
#define DH    64
#define TOPK  30
#define CANDN 40       // candidate margin: approx-top-40 superset of exact top-30
#define CANDCAP 2048   // per-row candidate capacity (~650 expected, r7 post-mortem)
#define ATT_SCALE 0.25f
#define LN_EPS 1e-5f

typedef __attribute__((ext_vector_type(8))) short bf16x8;  // 8 bf16 in 4 VGPRs
typedef __attribute__((ext_vector_type(4))) float f32x4;

static __device__ __forceinline__ ushort f2bf(float f) {   // RNE
    uint x = __float_as_uint(f);
    return (ushort)((x + 0x7FFFu + ((x >> 16) & 1u)) >> 16);
}
static __device__ __forceinline__ bf16x8 load_frag(const ushort* p) {
    union { int4 i; bf16x8 f; } u;
    u.i = *reinterpret_cast<const int4*>(p);
    return u.f;
}
static __device__ __forceinline__ uint s16key(uint u) {    // bf16 bits -> sortable u16
    return (u & 0x8000u) ? (u ^ 0xFFFFu) : (u | 0x8000u);
}

// ---------------------------------------------------------------------------
// Fused q+k fp32 GEMM NT (exactness needed for rescoring).
// ---------------------------------------------------------------------------
#define BK 32
__global__ __launch_bounds__(256) void qk_gemm_f32(
    const float* __restrict__ query_in, const float* __restrict__ key_in,
    const float* __restrict__ Wq, const float* __restrict__ bq,
    const float* __restrict__ Wk, const float* __restrict__ bk,
    float* __restrict__ qf, float* __restrict__ kf,
    ushort* __restrict__ qb, ushort* __restrict__ kb)
{
    const int j0g = blockIdx.x * 64;          // 0..511
    const int sel = j0g >> 8;                 // 0=q, 1=k
    const int j0  = j0g & 255;
    const float* A    = sel ? key_in : query_in;
    const float* W    = sel ? Wk : Wq;
    const float* bias = sel ? bk : bq;
    float*  outF = sel ? kf : qf;
    ushort* outB = sel ? kb : qb;

    __shared__ float As[BK][64 + 4];
    __shared__ float Ws[BK][64 + 4];
    const int tid = threadIdx.x;
    const int tx = tid & 15;
    const int ty = tid >> 4;
    const int i0 = blockIdx.y * 64;

    float acc[4][4];
#pragma unroll
    for (int r = 0; r < 4; r++)
#pragma unroll
        for (int c = 0; c < 4; c++) acc[r][c] = 0.f;

    for (int k0 = 0; k0 < DIM; k0 += BK) {
#pragma unroll
        for (int u = 0; u < 2; u++) {
            const int f = u * 256 + tid;
            const int r = f >> 3;
            const int c = (f & 7) * 4;
            float4 va = *reinterpret_cast<const float4*>(A + (size_t)(i0 + r) * DIM + k0 + c);
            As[c + 0][r] = va.x; As[c + 1][r] = va.y;
            As[c + 2][r] = va.z; As[c + 3][r] = va.w;
            float4 vw = *reinterpret_cast<const float4*>(W + (size_t)(j0 + r) * DIM + k0 + c);
            Ws[c + 0][r] = vw.x; Ws[c + 1][r] = vw.y;
            Ws[c + 2][r] = vw.z; Ws[c + 3][r] = vw.w;
        }
        __syncthreads();
#pragma unroll
        for (int kk = 0; kk < BK; kk++) {
            const float4 a4 = *reinterpret_cast<const float4*>(&As[kk][ty * 4]);
            const float4 b4 = *reinterpret_cast<const float4*>(&Ws[kk][tx * 4]);
            const float ar[4] = {a4.x, a4.y, a4.z, a4.w};
            const float br[4] = {b4.x, b4.y, b4.z, b4.w};
#pragma unroll
            for (int r = 0; r < 4; r++)
#pragma unroll
                for (int c = 0; c < 4; c++) acc[r][c] += ar[r] * br[c];
        }
        __syncthreads();
    }

#pragma unroll
    for (int r = 0; r < 4; r++) {
        const int gi = i0 + ty * 4 + r;
#pragma unroll
        for (int c = 0; c < 4; c++) {
            const int gj = j0 + tx * 4 + c;
            float v = acc[r][c] + bias[gj];
            outF[(size_t)gi * DIM + gj] = v;
            outB[(size_t)gi * DIM + gj] = f2bf(v);
        }
    }
}

// ---------------------------------------------------------------------------
// Cast fp32->bf16 (value_in, Wv, Wo) + zero-init rowmax/cnt (128 KB).
// ---------------------------------------------------------------------------
#define NCAST 294912          // 262144 + 16384 + 16384 float4 tasks
#define NINIT 8192            // 32768 u32 / 4
__global__ __launch_bounds__(256) void cast_init_kernel(
    const float* __restrict__ value_in, const float* __restrict__ Wv,
    const float* __restrict__ Wo, ushort* __restrict__ value_b,
    ushort* __restrict__ Wv_b, ushort* __restrict__ Wo_b,
    uint4* __restrict__ initz)
{
    const int id4 = blockIdx.x * 256 + threadIdx.x;
    if (id4 >= NCAST) {
        initz[id4 - NCAST] = (uint4){0u, 0u, 0u, 0u};
        return;
    }
    const int NV = 262144, NW = 16384;
    const float* src; ushort* dst; int off;
    if (id4 < NV)            { src = value_in; dst = value_b; off = id4; }
    else if (id4 < NV + NW)  { src = Wv; dst = Wv_b; off = id4 - NV; }
    else                     { src = Wo; dst = Wo_b; off = id4 - NV - NW; }
    float4 v = reinterpret_cast<const float4*>(src)[off];
    ushort4 o = {f2bf(v.x), f2bf(v.y), f2bf(v.z), f2bf(v.w)};
    reinterpret_cast<ushort4*>(dst)[off] = o;
}

// ---------------------------------------------------------------------------
// bf16 MFMA GEMM NT (v-projection and out-projection).
// ---------------------------------------------------------------------------
__global__ __launch_bounds__(256) void mfma_gemm(
    const ushort* __restrict__ A, const ushort* __restrict__ B,
    const float* __restrict__ bias, const float* __restrict__ addX,
    float* __restrict__ outF)
{
    const int lane = threadIdx.x & 63;
    const int wv   = threadIdx.x >> 6;
    const int i0   = blockIdx.y * 64 + wv * 16;
    const int j0   = blockIdx.x * 64;
    const int r = lane & 15, q = lane >> 4;

    f32x4 acc[4];
#pragma unroll
    for (int b = 0; b < 4; b++) acc[b] = (f32x4){0.f, 0.f, 0.f, 0.f};

#pragma unroll
    for (int ks = 0; ks < 8; ks++) {
        const int kk = ks * 32 + q * 8;
        bf16x8 af = load_frag(A + (size_t)(i0 + r) * DIM + kk);
        bf16x8 bfr[4];
#pragma unroll
        for (int jt = 0; jt < 4; jt++)
            bfr[jt] = load_frag(B + (size_t)(j0 + jt * 16 + r) * DIM + kk);
#pragma unroll
        for (int jt = 0; jt < 4; jt++)
            acc[jt] = __builtin_amdgcn_mfma_f32_16x16x32_bf16(af, bfr[jt], acc[jt], 0, 0, 0);
    }

#pragma unroll
    for (int jt = 0; jt < 4; jt++) {
        const int gj = j0 + jt * 16 + r;          // col = lane&15
        const float bv = bias[gj];
#pragma unroll
        for (int rg = 0; rg < 4; rg++) {          // row = (lane>>4)*4+reg
            const int gi = i0 + q * 4 + rg;
            float v = acc[jt][rg] + bv;
            if (addX) v += addX[(size_t)gi * DIM + gj];
            outF[(size_t)gi * DIM + gj] = v;
        }
    }
}

// ---------------------------------------------------------------------------
// Shared MFMA score-tile body: 32 rows x 128 cols per wave (one head slice).
// ---------------------------------------------------------------------------
static __device__ __forceinline__ void score_tile(
    const ushort* qb, const ushort* kb, int i0, int j0, int koff,
    int r, int q, f32x4 acc[2][8])
{
#pragma unroll
    for (int a = 0; a < 2; a++)
#pragma unroll
        for (int b = 0; b < 8; b++) acc[a][b] = (f32x4){0.f, 0.f, 0.f, 0.f};
#pragma unroll
    for (int ks = 0; ks < 2; ks++) {
        const int kk = koff + ks * 32 + q * 8;
        bf16x8 af[2], bfr[8];
#pragma unroll
        for (int mt = 0; mt < 2; mt++)
            af[mt] = load_frag(qb + (size_t)(i0 + mt * 16 + r) * DIM + kk);
#pragma unroll
        for (int jt = 0; jt < 8; jt++)
            bfr[jt] = load_frag(kb + (size_t)(j0 + jt * 16 + r) * DIM + kk);
#pragma unroll
        for (int mt = 0; mt < 2; mt++)
#pragma unroll
            for (int jt = 0; jt < 8; jt++)
                acc[mt][jt] = __builtin_amdgcn_mfma_f32_16x16x32_bf16(
                    af[mt], bfr[jt], acc[mt][jt], 0, 0, 0);
    }
}

// ---------------------------------------------------------------------------
// Pass 1: per-row max approx-score key via shfl-max + global atomicMax.
// ---------------------------------------------------------------------------
__global__ __launch_bounds__(256) void scores_max(
    const ushort* __restrict__ qb, const ushort* __restrict__ kb,
    uint* __restrict__ rowmaxU)
{
    const int lane = threadIdx.x & 63;
    const int wv   = threadIdx.x >> 6;
    const int h    = blockIdx.z;
    const int i0   = blockIdx.y * 128 + wv * 32;
    const int j0   = blockIdx.x * 128;
    const int r = lane & 15, q = lane >> 4;

    f32x4 acc[2][8];
    score_tile(qb, kb, i0, j0, h * DH, r, q, acc);

#pragma unroll
    for (int mt = 0; mt < 2; mt++)
#pragma unroll
        for (int rg = 0; rg < 4; rg++) {
            float m = acc[mt][0][rg];
#pragma unroll
            for (int jt = 1; jt < 8; jt++) m = fmaxf(m, acc[mt][jt][rg]);
#pragma unroll
            for (int off = 1; off < 16; off <<= 1)
                m = fmaxf(m, __shfl_xor(m, off));
            if (r == 0) {
                const int row = h * N_TOK + i0 + mt * 16 + q * 4 + rg;
                atomicMax(&rowmaxU[row], s16key(f2bf(m)));
            }
        }
}

// ---------------------------------------------------------------------------
// Pass 2: recompute identical scores; append keys within 255 ulps of the
// FINAL row max as (key<<12 | j). One atomicAdd reservation per
// (row, wave-tile) via 16-lane-group prefix sum (r7's 10.6M same-address
// atomics -> 0.5M scattered ones).
// ---------------------------------------------------------------------------
__global__ __launch_bounds__(256) void scores_cand(
    const ushort* __restrict__ qb, const ushort* __restrict__ kb,
    const uint* __restrict__ rowmaxU, uint* __restrict__ cntU,
    uint* __restrict__ candb)
{
    const int lane = threadIdx.x & 63;
    const int wv   = threadIdx.x >> 6;
    const int h    = blockIdx.z;
    const int i0   = blockIdx.y * 128 + wv * 32;
    const int j0   = blockIdx.x * 128;
    const int r = lane & 15, q = lane >> 4;

    f32x4 acc[2][8];
    score_tile(qb, kb, i0, j0, h * DH, r, q, acc);

#pragma unroll
    for (int mt = 0; mt < 2; mt++)
#pragma unroll
        for (int rg = 0; rg < 4; rg++) {
            const int row = h * N_TOK + i0 + mt * 16 + q * 4 + rg;
            const uint mxr = rowmaxU[row];

            uint keys8[8];
            uint amask = 0;
#pragma unroll
            for (int jt = 0; jt < 8; jt++) {
                keys8[jt] = s16key(f2bf(acc[mt][jt][rg]));
                if (mxr - keys8[jt] < 255u) amask |= (1u << jt);
            }
            const uint nc = (uint)__popc(amask);

            // inclusive prefix over the 16 r-lanes of this q-group
            uint pref = nc;
#pragma unroll
            for (int d = 1; d < 16; d <<= 1) {
                uint y = (uint)__shfl_up((int)pref, d);
                if ((lane & 15) >= d) pref += y;
            }
            const uint total = (uint)__shfl((int)pref, lane | 15);
            const uint excl  = pref - nc;

            uint base = 0;
            if ((lane & 15) == 15 && total > 0)
                base = atomicAdd(&cntU[row], total);
            base = (uint)__shfl((int)base, lane | 15);

            uint k = 0;
#pragma unroll
            for (int jt = 0; jt < 8; jt++) {
                if ((amask >> jt) & 1u) {
                    const uint pos = base + excl + k;
                    if (pos < CANDCAP)
                        candb[(size_t)row * CANDCAP + pos] =
                            (keys8[jt] << 12) | (uint)(j0 + jt * 16 + r);
                    k++;
                }
            }
        }
}

// ---------------------------------------------------------------------------
// Selection v6: two sweeps over <=2048 candidates/row (no register arrays).
// Sweep 1: histogram ulp-distances. Scan -> rank-40 threshold. Sweep 2:
// compact >= T. Exact fp32 rescore; bitonic sort; softmax; ctx + fused attn
// row write. Wave-uniform exact full-row fallback if cnt<40 or overflow.
// ---------------------------------------------------------------------------
__global__ __launch_bounds__(256) void select_kernel(
    const uint* __restrict__ rowmaxU, const uint* __restrict__ cntU,
    const uint* __restrict__ candb, const float* __restrict__ qf,
    const float* __restrict__ kf, const float* __restrict__ vf,
    float* __restrict__ pval, int* __restrict__ pidx,
    ushort* __restrict__ ctxb, float* __restrict__ attnRow)
{
    const int lane = threadIdx.x & 63;
    const int wv   = threadIdx.x >> 6;
    const int row  = blockIdx.x * 4 + wv;      // 0..16383
    const int h    = row >> 12;
    const int i    = row & (N_TOK - 1);

    __shared__ uint  hist[4][256];
    __shared__ uint  cand[4][64];
    __shared__ uint  ccnt[4];
    __shared__ float pw[4][TOPK];
    __shared__ int   jw[4][TOPK];
    __shared__ __align__(16) float qsh[4][DH];

    qsh[wv][lane] = qf[(size_t)i * DIM + h * DH + lane];
    if (lane == 0) ccnt[wv] = 0;
#pragma unroll
    for (int b = 0; b < 4; b++) hist[wv][b * 64 + lane] = 0u;  // stride-64: free

    const uint cnt = cntU[row];
    const uint mxr = rowmaxU[row];
    const uint* crow = candb + (size_t)row * CANDCAP;

    // early coalesced zero of the final attn row (drains while we compute)
    if (attnRow) {
        float4* rowg = reinterpret_cast<float4*>(attnRow + (size_t)row * N_TOK);
        const float4 z = {0.f, 0.f, 0.f, 0.f};
#pragma unroll
        for (int tt = 0; tt < 16; tt++) rowg[tt * 64 + lane] = z;
    }

    if (cnt >= CANDN && cnt <= CANDCAP) {
        // -------- primary: sweep 1 = histogram (d<=254 by construction) ----
        for (int e = lane; e < (int)cnt; e += 64) {
            const uint w = crow[e];
            atomicAdd(&hist[wv][mxr - (w >> 12)], 1u);
        }
        // prefix-scan bins, find rank-CANDN edge
        const uint c0 = hist[wv][lane * 4 + 0];
        const uint c1 = hist[wv][lane * 4 + 1];
        const uint c2 = hist[wv][lane * 4 + 2];
        const uint c3 = hist[wv][lane * 4 + 3];
        const uint segs = c0 + c1 + c2 + c3;
        uint scan = segs;
#pragma unroll
        for (int d = 1; d < 64; d <<= 1) {
            uint y = (uint)__shfl_up((int)scan, d);
            if (lane >= d) scan += y;
        }
        const uint excl = scan - segs;
        const bool crossing = (excl < CANDN) && (scan >= CANDN);
        unsigned long long bal = __ballot(crossing);
        int t = 254;                      // degenerate-safe default
        if (bal != 0ull) {
            const int srcLane = __ffsll(bal) - 1;
            int tloc = lane * 4;
            if (crossing) {
                uint cum = excl + c0;
                if (cum < CANDN) { tloc++; cum += c1;
                    if (cum < CANDN) { tloc++; cum += c2;
                        if (cum < CANDN) { tloc++; } } }
            }
            t = __shfl(tloc, srcLane);
        }
        const uint T = mxr - (uint)t;
        // -------- sweep 2: compact (candb row is L2-hot) -------------------
        for (int e = lane; e < (int)cnt; e += 64) {
            const uint w = crow[e];
            if ((w >> 12) >= T) {
                uint pos = atomicAdd(&ccnt[wv], 1u);
                if (pos < 64u) cand[wv][pos] = w & 0xFFFu;
            }
        }
    } else {
        // -------- fallback: exact fp32 full-row recompute (~never) ---------
        uint kwf[32];
        const float4* qr = reinterpret_cast<const float4*>(qsh[wv]);
        for (int tt = 0; tt < 64; tt++) {
            const int j = tt * 64 + lane;
            const float4* kr = reinterpret_cast<const float4*>(kf + (size_t)j * DIM + h * DH);
            float s = 0.f;
#pragma unroll
            for (int d = 0; d < 16; d++) {
                float4 a = qr[d], bb = kr[d];
                s += a.x * bb.x; s += a.y * bb.y; s += a.z * bb.z; s += a.w * bb.w;
            }
            const uint key = s16key(f2bf(s));
            if (tt & 1) kwf[tt >> 1] |= key << 16;
            else        kwf[tt >> 1] = key;
        }
        uint lo = 0;
#pragma unroll
        for (int b = 15; b >= 0; b--) {
            uint trial = lo | (1u << b);
            int c = 0;
#pragma unroll
            for (int w = 0; w < 32; w++) {
                c += ((kwf[w] & 0xFFFFu) >= trial) ? 1 : 0;
                c += ((kwf[w] >> 16)     >= trial) ? 1 : 0;
            }
#pragma unroll
            for (int off = 32; off; off >>= 1) c += __shfl_xor(c, off);
            if (c >= CANDN) lo = trial;
        }
        for (int tt = 0; tt < 64; tt++) {
            const uint key = (tt & 1) ? (kwf[tt >> 1] >> 16) : (kwf[tt >> 1] & 0xFFFFu);
            if (key >= lo) {
                uint pos = atomicAdd(&ccnt[wv], 1u);
                if (pos < 64u) cand[wv][pos] = (uint)(tt * 64 + lane);
            }
        }
    }

    const int m = (int)min(ccnt[wv], 64u);

    // exact fp32 rescore of candidate `lane`
    unsigned long long ukey = 0ull;
    if (lane < m) {
        const int j = (int)cand[wv][lane];
        const float4* kr = reinterpret_cast<const float4*>(kf + (size_t)j * DIM + h * DH);
        const float4* qr = reinterpret_cast<const float4*>(qsh[wv]);
        float s = 0.f;
#pragma unroll
        for (int d = 0; d < 16; d++) {
            float4 a = qr[d], bb = kr[d];
            s += a.x * bb.x; s += a.y * bb.y; s += a.z * bb.z; s += a.w * bb.w;
        }
        uint bits = __float_as_uint(s);
        uint s32 = (bits & 0x80000000u) ? ~bits : (bits | 0x80000000u);
        ukey = ((unsigned long long)s32 << 12) | (unsigned long long)(4095 - j);
    }

    // bitonic sort ascending (key: score, tie: smaller index wins)
#pragma unroll
    for (int k = 2; k <= 64; k <<= 1) {
#pragma unroll
        for (int jj = k >> 1; jj > 0; jj >>= 1) {
            unsigned long long o = __shfl_xor(ukey, jj);
            bool keepMax = ((lane & jj) != 0) ^ ((lane & k) != 0);
            ukey = keepMax ? (ukey > o ? ukey : o) : (ukey < o ? ukey : o);
        }
    }

    const int rank = 63 - lane;
    const int jsel = 4095 - (int)(ukey & 0xFFFull);
    uint s32b = (uint)(ukey >> 12);
    uint fb = (s32b & 0x80000000u) ? (s32b ^ 0x80000000u) : ~s32b;
    const float sc = __uint_as_float(fb);
    const float stop = __shfl(sc, 63);

    float e = (rank < TOPK) ? __expf((sc - stop) * ATT_SCALE) : 0.f;
    float esum = e;
#pragma unroll
    for (int off = 32; off; off >>= 1) esum += __shfl_xor(esum, off);
    const float p = e / esum;

    if (rank < TOPK) {
        pw[wv][rank] = p; jw[wv][rank] = jsel;
        if (pval) {
            pval[(size_t)row * 32 + rank] = p;
            pidx[(size_t)row * 32 + rank] = jsel;
        }
    }

    // sparse ctx
    float a = 0.f;
#pragma unroll
    for (int c = 0; c < TOPK; c++)
        a += pw[wv][c] * vf[(size_t)jw[wv][c] * DIM + h * DH + lane];
    ctxb[(size_t)i * DIM + h * DH + lane] = f2bf(a);

    if (attnRow) {
        asm volatile("s_waitcnt vmcnt(0)" ::: "memory");   // zeros drained
        if (rank < TOPK)
            attnRow[(size_t)row * N_TOK + jsel] = p;
    }
}

// ---------------------------------------------------------------------------
// attn_write (small-ws fallback path only).
// ---------------------------------------------------------------------------
__global__ __launch_bounds__(256) void attn_write(
    const float* __restrict__ pval, const int* __restrict__ pidx,
    float* __restrict__ attnF)
{
    __shared__ __align__(16) float rb[4][N_TOK];
    const int tid = threadIdx.x;
    const int r0 = blockIdx.x * 4;

    float4* rb4 = reinterpret_cast<float4*>(&rb[0][0]);
    const float4 z = {0.f, 0.f, 0.f, 0.f};
#pragma unroll
    for (int t = 0; t < 16; t++) rb4[t * 256 + tid] = z;
    __syncthreads();
    if (tid < 4 * TOPK) {
        const int w = tid / TOPK, c = tid % TOPK;
        rb[w][pidx[(size_t)(r0 + w) * 32 + c]] = pval[(size_t)(r0 + w) * 32 + c];
    }
    __syncthreads();
#pragma unroll
    for (int w = 0; w < 4; w++) {
        float4* grow = reinterpret_cast<float4*>(attnF + (size_t)(r0 + w) * N_TOK);
#pragma unroll
        for (int t = 0; t < 4; t++)
            grow[t * 256 + tid] = rb4[w * 1024 + t * 256 + tid];
    }
}

// ---------------------------------------------------------------------------
// Row LayerNorm (biased var), in-place on fp32 resid. One wave per row.
// ---------------------------------------------------------------------------
__global__ __launch_bounds__(64) void ln_kernel(
    float* __restrict__ resb, const float* __restrict__ g,
    const float* __restrict__ b)
{
    const int i = blockIdx.x, lane = threadIdx.x;
    float4* rowp = reinterpret_cast<float4*>(resb + (size_t)i * DIM);
    float4 x = rowp[lane];
    float s  = x.x + x.y + x.z + x.w;
    float sq = x.x * x.x + x.y * x.y + x.z * x.z + x.w * x.w;
#pragma unroll
    for (int off = 32; off; off >>= 1) {
        s  += __shfl_xor(s, off);
        sq += __shfl_xor(sq, off);
    }
    const float mu  = s * (1.f / DIM);
    const float var = sq * (1.f / DIM) - mu * mu;
    const float rstd = rsqrtf(var + LN_EPS);
    const int col = lane * 4;
    float4 o;
    o.x = (x.x - mu) * rstd * g[col + 0] + b[col + 0];
    o.y = (x.y - mu) * rstd * g[col + 1] + b[col + 1];
    o.z = (x.z - mu) * rstd * g[col + 2] + b[col + 2];
    o.w = (x.w - mu) * rstd * g[col + 3] + b[col + 3];
    rowp[lane] = o;
}

// ---------------------------------------------------------------------------
extern "C" void kernel_launch(void* const* d_in, const int* in_sizes, int n_in,
                              void* d_out, int out_size, void* d_ws, size_t ws_size,
                              hipStream_t stream)
{
    const float* key_in   = (const float*)d_in[0];
    const float* value_in = (const float*)d_in[1];
    const float* query_in = (const float*)d_in[2];
    const float* Wq = (const float*)d_in[3];
    const float* bq = (const float*)d_in[4];
    const float* Wk = (const float*)d_in[5];
    const float* bk = (const float*)d_in[6];
    const float* Wv = (const float*)d_in[7];
    const float* bv = (const float*)d_in[8];
    const float* Wo = (const float*)d_in[9];
    const float* bo = (const float*)d_in[10];
    const float* ln_g = (const float*)d_in[11];
    const float* ln_b = (const float*)d_in[12];

    float* outF  = (float*)d_out;                     // (N, D) fp32
    float* attnF = outF + (size_t)N_TOK * DIM;        // (H, N, N) fp32

    // scratch layout: candb 128M | qf 4M | kf 4M | vf 4M | qb 2M | kb 2M |
    // ctxb 2M | value_b 2M | Wv_b/Wo_b 256K | rowmax 64K | cnt 64K | pval/pidx
    const size_t MB = 1u << 20;
    const size_t CANDB_B = (size_t)NH * N_TOK * CANDCAP * 4;   // 128 MB
    const size_t NEED = CANDB_B + 28 * MB;
    const bool usews = (ws_size >= NEED);
    char* base = usews ? (char*)d_ws : (char*)attnF;  // fallback: inside attnF

    uint*   candb   = (uint*)base;
    float*  qf      = (float*)(base + CANDB_B);
    float*  kf      = (float*)(base + CANDB_B + 4 * MB);
    float*  vf      = (float*)(base + CANDB_B + 8 * MB);
    ushort* qb      = (ushort*)(base + CANDB_B + 12 * MB);
    ushort* kb      = (ushort*)(base + CANDB_B + 14 * MB);
    ushort* ctxb    = (ushort*)(base + CANDB_B + 16 * MB);
    ushort* value_b = (ushort*)(base + CANDB_B + 18 * MB);
    ushort* Wv_b    = (ushort*)(base + CANDB_B + 20 * MB);
    ushort* Wo_b    = (ushort*)(base + CANDB_B + 20 * MB + 131072);
    uint*   rowmaxU = (uint*)(base + CANDB_B + 21 * MB);
    uint*   cntU    = (uint*)(base + CANDB_B + 21 * MB + 65536);
    float*  pval    = (float*)(base + CANDB_B + 22 * MB);   // fallback path only
    int*    pidx    = (int*)(base + CANDB_B + 24 * MB);

    cast_init_kernel<<<(NCAST + NINIT) / 256, 256, 0, stream>>>(
        value_in, Wv, Wo, value_b, Wv_b, Wo_b, (uint4*)rowmaxU);
    qk_gemm_f32<<<dim3(8, 64), 256, 0, stream>>>(
        query_in, key_in, Wq, bq, Wk, bk, qf, kf, qb, kb);
    mfma_gemm<<<dim3(4, 64), 256, 0, stream>>>(value_b, Wv_b, bv, nullptr, vf);

    scores_max<<<dim3(32, 32, NH), 256, 0, stream>>>(qb, kb, rowmaxU);
    scores_cand<<<dim3(32, 32, NH), 256, 0, stream>>>(qb, kb, rowmaxU, cntU, candb);

    if (usews) {
        select_kernel<<<dim3(N_TOK * NH / 4), 256, 0, stream>>>(
            rowmaxU, cntU, candb, qf, kf, vf, nullptr, nullptr, ctxb, attnF);
        mfma_gemm<<<dim3(4, 64), 256, 0, stream>>>(ctxb, Wo_b, bo, query_in, outF);
        ln_kernel<<<N_TOK, 64, 0, stream>>>(outF, ln_g, ln_b);
    } else {
        select_kernel<<<dim3(N_TOK * NH / 4), 256, 0, stream>>>(
            rowmaxU, cntU, candb, qf, kf, vf, pval, pidx, ctxb, nullptr);
        mfma_gemm<<<dim3(4, 64), 256, 0, stream>>>(ctxb, Wo_b, bo, query_in, outF);
        ln_kernel<<<N_TOK, 64, 0, stream>>>(outF, ln_g, ln_b);
        attn_write<<<N_TOK * NH / 4, 256, 0, stream>>>(pval, pidx, attnF);
    }
}